// Round 13
// baseline (139.036 us; speedup 1.0000x reference)
//
#include <hip/hip_runtime.h>
#include <hip/hip_bf16.h>
#include <math.h>

#define NS 4096          // samples per view
#define NI 8192          // total instances (2 views)
#define DIM 512
#define TEMP_INV 2.0f    // 1/t, t = 0.5
#define BM 128           // supertile rows
#define BN 256           // supertile cols (2 x 128 halves)
#define NBI (NI / BM)    // 64 row-blocks
#define NBJ (NI / BN)    // 32 col-blocks
#define NSUP 1056        // sum_{bi=0}^{63} (32 - bi/2) supertiles
#define BK 64            // k-elems staged per step
#define NSTG (DIM / BK)  // 8 steps

typedef short v8s __attribute__((ext_vector_type(8)));   // 8 bf16 (4 VGPRs)
typedef float v4f __attribute__((ext_vector_type(4)));   // 4 fp32 acc

// async global->LDS, 16B per lane. LDS dest is wave-uniform base + lane*16.
__device__ __forceinline__ void gld16(const void* g, void* l) {
    __builtin_amdgcn_global_load_lds(
        (const __attribute__((address_space(1))) void*)g,
        (__attribute__((address_space(3))) void*)l, 16, 0, 0);
}

// ---------------------------------------------------------------------------
// Kernel 1: norms + positive dots (fp32), cast X -> bf16; also zeros rowsum.
// ---------------------------------------------------------------------------
__global__ __launch_bounds__(256) void prep_kernel(
        const float* __restrict__ x1, const float* __restrict__ x2,
        __hip_bfloat16* __restrict__ Xb, float* __restrict__ rnorm,
        float* __restrict__ posdot, float* __restrict__ rowsum) {
    const int t = threadIdx.x;
    if (t < 4) rowsum[blockIdx.x * 4 + t] = 0.f;   // 2048 blocks x 4 = NI
    const int sub = t >> 7;
    const int c4 = t & 127;
    const int i = blockIdx.x * 2 + sub;
    const float4 a = ((const float4*)(x1 + (size_t)i * DIM))[c4];
    const float4 b = ((const float4*)(x2 + (size_t)i * DIM))[c4];
    float s1 = a.x*a.x + a.y*a.y + a.z*a.z + a.w*a.w;
    float s2 = b.x*b.x + b.y*b.y + b.z*b.z + b.w*b.w;
    float dd = a.x*b.x + a.y*b.y + a.z*b.z + a.w*b.w;

    auto bfbits = [](float v) -> unsigned short {
        __hip_bfloat16 h = __float2bfloat16(v);
        return *(unsigned short*)&h;
    };
    ushort4 pa = { bfbits(a.x), bfbits(a.y), bfbits(a.z), bfbits(a.w) };
    ushort4 pb = { bfbits(b.x), bfbits(b.y), bfbits(b.z), bfbits(b.w) };
    ((ushort4*)(Xb + (size_t)i * DIM))[c4] = pa;
    ((ushort4*)(Xb + (size_t)(i + NS) * DIM))[c4] = pb;

    #pragma unroll
    for (int off = 32; off; off >>= 1) {
        s1 += __shfl_down(s1, off, 64);
        s2 += __shfl_down(s2, off, 64);
        dd += __shfl_down(dd, off, 64);
    }
    __shared__ float red[2][2][3];
    if ((t & 63) == 0) {
        const int w = (t >> 6) & 1;
        red[sub][w][0] = s1; red[sub][w][1] = s2; red[sub][w][2] = dd;
    }
    __syncthreads();
    if ((t & 127) == 0) {
        s1 = red[sub][0][0] + red[sub][1][0];
        s2 = red[sub][0][1] + red[sub][1][1];
        dd = red[sub][0][2] + red[sub][1][2];
        rnorm[i]      = 1.0f / sqrtf(s1);
        rnorm[i + NS] = 1.0f / sqrtf(s2);
        posdot[i] = dd;
    }
}

// ---------------------------------------------------------------------------
// Kernel 2: 128x256 supertiles of G = Xb*Xb^T (two 128-col halves/block).
// R12 retry with the spill fixed. R12 (acc[4][8], af[4]+bf[8] live) wrote
// 22 MB of scratch: 128 acc regs force the unified-file arch half to ~128,
// and 48 live frag regs + ~70 addressing/loop state exceeded it. THIS
// version processes B-columns in two batches of 4 per s2 substep:
// af[4]+bf[4] = 32 live frag regs (exactly R7's clean-compile liveness).
// MFMA count and per-acc accumulation order unchanged -> same numerics.
// Supertile rationale (R11): tile count 2080 -> 1056, fixed per-tile costs
// halve, LDS-read/FLOP -25%, FETCH measured 65 -> 53 GB (real).
// Diagonal logic per wave column-half: jblk = 2*bjj + wc vs bi:
//   above: row+col adds, negacc x2; diag: row only, x1; below: zeroed.
// Same proven 2-barrier single-buffer loop + swizzle (cs = kc^(row&7)).
// Epilogue scratch overlaid on dead staging -> LDS = 48 KB.
// Tripwire: WRITE_SIZE > 10 MB = spill = round void -> revert to R7.
// ---------------------------------------------------------------------------
__global__ __launch_bounds__(256, 2) void sim_kernel(
        const __hip_bfloat16* __restrict__ Xbh, const float* __restrict__ rnorm,
        float* __restrict__ rowsum, float* __restrict__ negpart) {
    // --- XCD-aware bijective swizzle: 1056 = 8 * 132 exactly
    const int raw = blockIdx.x;
    const int id = (raw & 7) * 132 + (raw >> 3);
    // --- decode id -> (bi, bjj): row-block bi 0..63, col-superblock bjj.
    int bi = 0, base = 0;
    while (id >= base + (NBJ - (bi >> 1))) { base += NBJ - (bi >> 1); ++bi; }
    const int bjj = (bi >> 1) + (id - base);
    const int i0 = bi * BM, j0 = bjj * BN;

    __shared__ __align__(16) char smem[2 * BM * BK + 2 * BN * BK];  // 48 KB
    short* stgA = (short*)smem;                      // [0, 16384) B
    short* stgB = (short*)(smem + 2 * BM * BK);      // [16384, 49152) B
    // epilogue overlay (staging dead by then):
    float* sRow = (float*)smem;                      // [2][128]  1 KB
    float* sCol = (float*)(smem + 1024);             // [2][256]  2 KB
    float* sNeg = (float*)(smem + 3072);             // [4]

    const int t = threadIdx.x;                 // 0..255
    const int lane = t & 63, wv = t >> 6;      // 4 waves
    const int wr = wv >> 1, wc = wv & 1;       // 2x2: rows 2x64, cols 2x128
    const int r16 = lane & 15, quad = lane >> 4;

    // per-wave column-half classification
    const int jblk = 2 * bjj + wc;             // 128-col tile index
    const bool above = (jblk > bi);
    const bool valid = (jblk >= bi);           // above or diagonal
    const float negscale = above ? 2.0f : (valid ? 1.0f : 0.0f);

    const short* X = reinterpret_cast<const short*>(Xbh);

    // --- staging bases (q-independent). Chunk lin = q*256 + t:
    // row = q*32 + (t>>3), slot cs = t&7 holds kc = cs ^ (row&7) =
    // (t&7)^((t>>3)&7). Global q-stride = 32 rows = 16384 shorts; LDS
    // q-stride = 2048 shorts. HW adds lane*16B.
    const int grow = t >> 3;                           // 0..31
    const int kc   = (t & 7) ^ (grow & 7);
    const int gA   = (i0 + grow) * DIM + kc * 8;       // short index
    const int gB   = (j0 + grow) * DIM + kc * 8;       // rows of B panel
    const int lbs  = wv * 512;                         // shorts; +q*2048

    // --- fragment read bases (bytes; frag-index adds 2048; s2 is ^0x40).
    const int slot = (quad ^ (r16 & 7)) * 16;
    const int aoff = (wr * 64  + r16) * 128 + slot;    // A rows wr*64+tt*16+r16
    const int boff = (wc * 128 + r16) * 128 + slot;    // B rows wc*128+tb*16+r16

    v4f acc[4][8];
    #pragma unroll
    for (int a = 0; a < 4; ++a)
        #pragma unroll
        for (int b = 0; b < 8; ++b)
            acc[a][b] = (v4f){0.f, 0.f, 0.f, 0.f};

    // --- main loop: 8 K-steps of BK=64, single-buffered (2-barrier)
    for (int s = 0; s < NSTG; ++s) {
        const int k0 = s * BK;
        __syncthreads();                       // prior iter's reads complete
        #pragma unroll
        for (int q = 0; q < 4; ++q)            // A: 128 rows = 16 KB
            gld16(X + gA + k0 + q * 16384, stgA + lbs + q * 2048);
        #pragma unroll
        for (int q = 0; q < 8; ++q)            // B: 256 rows = 32 KB
            gld16(X + gB + k0 + q * 16384, stgB + lbs + q * 2048);
        __syncthreads();                       // vmcnt drained -> tile ready
        #pragma unroll
        for (int s2 = 0; s2 < 2; ++s2) {
            const int x = s2 << 6;
            v8s af[4];
            #pragma unroll
            for (int tt = 0; tt < 4; ++tt)
                af[tt] = *(const v8s*)((const char*)stgA + ((aoff + tt * 2048) ^ x));
            #pragma unroll
            for (int half = 0; half < 2; ++half) {
                v8s bf[4];
                #pragma unroll
                for (int tb = 0; tb < 4; ++tb)
                    bf[tb] = *(const v8s*)((const char*)stgB +
                             ((boff + (half * 4 + tb) * 2048) ^ x));
                #pragma unroll
                for (int ta = 0; ta < 4; ++ta)
                    #pragma unroll
                    for (int tb = 0; tb < 4; ++tb)
                        acc[ta][half * 4 + tb] =
                            __builtin_amdgcn_mfma_f32_16x16x32_bf16(
                                af[ta], bf[tb], acc[ta][half * 4 + tb], 0, 0, 0);
            }
        }
    }

    __syncthreads();                           // staging dead; overlay safe

    // --- epilogue: sim2 = 2*D*r_i*r_j; masked (j==i, j==i^NS) -> exp = 1
    float rc[8];
    int colg[8];
    #pragma unroll
    for (int tb = 0; tb < 8; ++tb) {
        colg[tb] = j0 + wc * 128 + tb * 16 + r16;
        rc[tb] = rnorm[colg[tb]];
    }
    float negacc = 0.f;
    float colacc[8] = {0.f, 0.f, 0.f, 0.f, 0.f, 0.f, 0.f, 0.f};
    #pragma unroll
    for (int ta = 0; ta < 4; ++ta) {
        #pragma unroll
        for (int r = 0; r < 4; ++r) {
            const int rowl = wr * 64 + ta * 16 + quad * 4 + r;
            const int rowg = i0 + rowl;
            const float rr = rnorm[rowg] * TEMP_INV;
            float rowe = 0.f;
            #pragma unroll
            for (int tb = 0; tb < 8; ++tb) {
                const float sim2 = acc[ta][tb][r] * rr * rc[tb];
                const bool masked = (colg[tb] == rowg) || (colg[tb] == (rowg ^ NS));
                const float e = masked ? 1.0f : __expf(sim2);
                rowe   += e;
                negacc += masked ? 0.0f : sim2;
                colacc[tb] += e;
            }
            #pragma unroll
            for (int off = 1; off < 16; off <<= 1)
                rowe += __shfl_xor(rowe, off, 64);
            if (r16 == 0) sRow[wc * BM + rowl] = valid ? rowe : 0.f;
        }
    }
    #pragma unroll
    for (int tb = 0; tb < 8; ++tb) {
        colacc[tb] += __shfl_xor(colacc[tb], 16, 64);
        colacc[tb] += __shfl_xor(colacc[tb], 32, 64);
        if (quad == 0)
            sCol[wr * BN + wc * 128 + tb * 16 + r16] = above ? colacc[tb] : 0.f;
    }
    negacc *= negscale;
    #pragma unroll
    for (int off = 1; off < 64; off <<= 1)
        negacc += __shfl_xor(negacc, off, 64);
    if (lane == 0) sNeg[wv] = negacc;

    __syncthreads();

    if (t < BM)
        atomicAdd(&rowsum[i0 + t], sRow[t] + sRow[BM + t]);
    // cols: 256 entries, one thread each; gate by half's above-flag
    {
        const int h = t >> 7;                  // col half 0/1
        if (2 * bjj + h > bi)
            atomicAdd(&rowsum[j0 + t], sCol[t] + sCol[BN + t]);
    }
    if (t == 0)
        negpart[id] = sNeg[0] + sNeg[1] + sNeg[2] + sNeg[3];
}

// ---------------------------------------------------------------------------
// Kernel 3: final scalars. E_i = rowsum[i] (includes +2 from masked entries).
// ---------------------------------------------------------------------------
__global__ __launch_bounds__(1024) void final_kernel(
        const float* __restrict__ rowsum, const float* __restrict__ rnorm,
        const float* __restrict__ posdot, const float* __restrict__ negpart,
        float* __restrict__ out) {
    const int t = threadIdx.x;
    float lsum = 0.f, psum = 0.f, nsum = 0.f;
    #pragma unroll
    for (int i = t; i < NI; i += 1024) {
        const int s = i & (NS - 1);
        const float sp = posdot[s] * rnorm[i] * rnorm[i ^ NS] * TEMP_INV;
        const float E = rowsum[i];
        lsum += logf(expf(sp) + E) - sp;
        psum += sp;
    }
    for (int i = t; i < NSUP; i += 1024)
        nsum += negpart[i];
    __shared__ float red[3][16];
    #pragma unroll
    for (int off = 32; off; off >>= 1) {
        lsum += __shfl_down(lsum, off, 64);
        psum += __shfl_down(psum, off, 64);
        nsum += __shfl_down(nsum, off, 64);
    }
    if ((t & 63) == 0) {
        red[0][t >> 6] = lsum; red[1][t >> 6] = psum; red[2][t >> 6] = nsum;
    }
    __syncthreads();
    if (t == 0) {
        lsum = 0.f; psum = 0.f; nsum = 0.f;
        #pragma unroll
        for (int w = 0; w < 16; ++w) {
            lsum += red[0][w]; psum += red[1][w]; nsum += red[2][w];
        }
        out[0] = lsum / (float)NI;
        out[1] = psum / (float)NI;
        out[2] = nsum / ((float)NI * (float)(NI - 2));
    }
}

// ---------------------------------------------------------------------------
extern "C" void kernel_launch(void* const* d_in, const int* in_sizes, int n_in,
                              void* d_out, int out_size, void* d_ws, size_t ws_size,
                              hipStream_t stream) {
    const float* x1 = (const float*)d_in[0];
    const float* x2 = (const float*)d_in[1];
    float* out = (float*)d_out;

    char* ws = (char*)d_ws;
    __hip_bfloat16* Xb = (__hip_bfloat16*)ws;                 // NI*DIM*2 = 8 MB
    float* rnorm  = (float*)(ws + (size_t)NI * DIM * 2);      // NI
    float* posdot = rnorm + NI;                               // NS
    float* rowsum = posdot + NS;                              // NI (zeroed in prep)
    float* negpart = rowsum + NI;                             // NSUP (all written)

    prep_kernel<<<NS / 2, 256, 0, stream>>>(x1, x2, Xb, rnorm, posdot, rowsum);

    sim_kernel<<<NSUP, 256, 0, stream>>>(Xb, rnorm, rowsum, negpart);

    final_kernel<<<1, 1024, 0, stream>>>(rowsum, rnorm, posdot, negpart, out);
}

// Round 14
// 123.797 us; speedup vs baseline: 1.1231x; 1.1231x over previous
//
#include <hip/hip_runtime.h>
#include <hip/hip_bf16.h>
#include <math.h>

#define NS 4096          // samples per view
#define NI 8192          // total instances (2 views)
#define DIM 512
#define TEMP_INV 2.0f    // 1/t, t = 0.5
#define TILE 128         // output tile side
#define NBLK 64          // NI/TILE tile blocks per side
#define NTRI (NBLK * (NBLK + 1) / 2)   // 2080 upper-triangle tiles
#define BK 64            // k-elems staged per step
#define NSTG (DIM / BK)  // 8 stages

typedef short v8s __attribute__((ext_vector_type(8)));   // 8 bf16 (4 VGPRs)
typedef float v4f __attribute__((ext_vector_type(4)));   // 4 fp32 acc

// async global->LDS, 16B per lane. LDS dest is wave-uniform base + lane*16.
__device__ __forceinline__ void gld16(const void* g, void* l) {
    __builtin_amdgcn_global_load_lds(
        (const __attribute__((address_space(1))) void*)g,
        (__attribute__((address_space(3))) void*)l, 16, 0, 0);
}

// ---------------------------------------------------------------------------
// Kernel 1: norms + positive dots (fp32), cast X -> bf16; also zeros rowsum.
// ---------------------------------------------------------------------------
__global__ __launch_bounds__(256) void prep_kernel(
        const float* __restrict__ x1, const float* __restrict__ x2,
        __hip_bfloat16* __restrict__ Xb, float* __restrict__ rnorm,
        float* __restrict__ posdot, float* __restrict__ rowsum) {
    const int t = threadIdx.x;
    if (t < 4) rowsum[blockIdx.x * 4 + t] = 0.f;   // 2048 blocks x 4 = NI
    const int sub = t >> 7;
    const int c4 = t & 127;
    const int i = blockIdx.x * 2 + sub;
    const float4 a = ((const float4*)(x1 + (size_t)i * DIM))[c4];
    const float4 b = ((const float4*)(x2 + (size_t)i * DIM))[c4];
    float s1 = a.x*a.x + a.y*a.y + a.z*a.z + a.w*a.w;
    float s2 = b.x*b.x + b.y*b.y + b.z*b.z + b.w*b.w;
    float dd = a.x*b.x + a.y*b.y + a.z*b.z + a.w*b.w;

    auto bfbits = [](float v) -> unsigned short {
        __hip_bfloat16 h = __float2bfloat16(v);
        return *(unsigned short*)&h;
    };
    ushort4 pa = { bfbits(a.x), bfbits(a.y), bfbits(a.z), bfbits(a.w) };
    ushort4 pb = { bfbits(b.x), bfbits(b.y), bfbits(b.z), bfbits(b.w) };
    ((ushort4*)(Xb + (size_t)i * DIM))[c4] = pa;
    ((ushort4*)(Xb + (size_t)(i + NS) * DIM))[c4] = pb;

    #pragma unroll
    for (int off = 32; off; off >>= 1) {
        s1 += __shfl_down(s1, off, 64);
        s2 += __shfl_down(s2, off, 64);
        dd += __shfl_down(dd, off, 64);
    }
    __shared__ float red[2][2][3];
    if ((t & 63) == 0) {
        const int w = (t >> 6) & 1;
        red[sub][w][0] = s1; red[sub][w][1] = s2; red[sub][w][2] = dd;
    }
    __syncthreads();
    if ((t & 127) == 0) {
        s1 = red[sub][0][0] + red[sub][1][0];
        s2 = red[sub][0][1] + red[sub][1][1];
        dd = red[sub][0][2] + red[sub][1][2];
        rnorm[i]      = 1.0f / sqrtf(s1);
        rnorm[i + NS] = 1.0f / sqrtf(s2);
        posdot[i] = dd;
    }
}

// ---------------------------------------------------------------------------
// Kernel 2: upper-triangle 128x128 tiles of G = Xb*Xb^T — R7 configuration,
// the measured optimum after a 13-round exploration. 256 thr / 4 waves
// (2x2), wave tile 64x64 (acc[4][4]=64 regs), SINGLE 32 KB buffer, BK=64,
// 8 two-barrier K-steps, fully-folded immediate addressing, swizzle slot
// cs = kc^(row&7) (0 bank conflicts measured), XCD-bijective block swizzle.
// Compiles to VGPR 80, zero scratch; 58.2 us measured (R7).
// Ledger of refuted alternatives (all measured):
//   dbuf BK=32/64 (R9/R10/R0): co-residency already covers the drain; worse
//   BK=128 (R11: 70.4) / BK=32 (R9: 65.0): 8 pairs is the U-curve minimum
//   8-phase counted-vmcnt (R6: 88) + 256^2 1-blk/CU (R2/R5: ~84): lockstep
//   __launch_bounds__(256,4) (R1/R8): allocator caps 64 arch regs -> spill
//   128x256 supertile acc[4][8] (R12/R13): register-file overflow, 22 MB
//   fused final w/ __threadfence (R10): L2 writeback storm on 8 XCDs, 2x
// No pipe >40% here (Mfma 24, VALU 29, LDS ~39, HBM 15, occ 25) but every
// utilization-raising lever hits a measured HW constraint: this is the
// practical latency-structure ceiling for this shape at HIP source level.
// ---------------------------------------------------------------------------
__global__ __launch_bounds__(256, 3) void sim_kernel(
        const __hip_bfloat16* __restrict__ Xbh, const float* __restrict__ rnorm,
        float* __restrict__ rowsum, float* __restrict__ negpart) {
    // --- XCD-aware bijective swizzle: 2080 = 8 * 260 exactly
    const int raw = blockIdx.x;
    const int id = (raw & 7) * 260 + (raw >> 3);
    // --- triangular decode: id -> (bi, bj), bi<=bj (round-0 proven, NBLK=64)
    int bi = (int)((129.0f - sqrtf(16641.0f - 8.0f * (float)id)) * 0.5f);
    int base = bi * (129 - bi) / 2;
    if (id < base)                     { --bi; base = bi * (129 - bi) / 2; }
    else if (id >= base + (64 - bi))   { ++bi; base = bi * (129 - bi) / 2; }
    const int bj = bi + (id - base);
    const bool offdiag = (bj != bi);
    const int i0 = bi * TILE, j0 = bj * TILE;

    __shared__ __align__(16) short lds[2][TILE * BK];  // [A/B], 32 KB total
    __shared__ float sRow[2][TILE];            // [wc][row]
    __shared__ float sCol[2][TILE];            // [wr][col]
    __shared__ float sNeg[4];

    const int t = threadIdx.x;                 // 0..255
    const int lane = t & 63, wv = t >> 6;      // 4 waves
    const int wr = wv >> 1, wc = wv & 1;       // 2x2 wave grid, 64x64 each
    const int r16 = lane & 15, quad = lane >> 4;

    const short* X = reinterpret_cast<const short*>(Xbh);

    // --- staging bases (q-independent; q strides are immediates).
    // instr q covers chunks lin = q*256 + t: row = q*32 + (t>>3),
    // slot cs = t&7 holds global k-chunk kc = cs ^ (row&7) (q*32 preserves
    // row&7). Global: q adds 32 rows = 16384 shorts; LDS: q adds 2048 shorts.
    const int grow = t >> 3;                           // 0..31
    const int kc   = (t & 7) ^ (grow & 7);
    const int gA   = (i0 + grow) * DIM + kc * 8;       // short index
    const int gB   = (j0 + grow) * DIM + kc * 8;
    const int lbs  = wv * 512;                         // shorts; +q*2048

    // --- fragment read bases (bytes; tt adds 2048, s2 is ^64, B at +16384).
    // row&7 == r16&7 (wr*64, tt*16 are 0 mod 8), so slot is tt-independent.
    const int slot = (quad ^ (r16 & 7)) * 16;
    const int aoff = (wr * 64 + r16) * 128 + slot;
    const int boff = (wc * 64 + r16) * 128 + slot;

    v4f acc[4][4];
    #pragma unroll
    for (int a = 0; a < 4; ++a)
        #pragma unroll
        for (int b = 0; b < 4; ++b)
            acc[a][b] = (v4f){0.f, 0.f, 0.f, 0.f};

    const char* ldsb = (const char*)&lds[0][0];

    // --- main loop: 8 K-steps of BK=64, single-buffered (m97 2-barrier)
    for (int s = 0; s < NSTG; ++s) {
        const int k0 = s * BK;
        __syncthreads();                       // prior iter's reads complete
        #pragma unroll
        for (int q = 0; q < 4; ++q) {
            gld16(X + gA + k0 + q * 16384, &lds[0][lbs + q * 2048]);
            gld16(X + gB + k0 + q * 16384, &lds[1][lbs + q * 2048]);
        }
        __syncthreads();                       // vmcnt drained -> tile ready
        #pragma unroll
        for (int s2 = 0; s2 < 2; ++s2) {
            v8s af[4], bf[4];
            #pragma unroll
            for (int tt = 0; tt < 4; ++tt) {
                af[tt] = *(const v8s*)(ldsb + ((aoff + tt * 2048) ^ (s2 * 64)));
                bf[tt] = *(const v8s*)(ldsb + 16384 + ((boff + tt * 2048) ^ (s2 * 64)));
            }
            #pragma unroll
            for (int ta = 0; ta < 4; ++ta)
                #pragma unroll
                for (int tb = 0; tb < 4; ++tb)
                    acc[ta][tb] = __builtin_amdgcn_mfma_f32_16x16x32_bf16(
                        af[ta], bf[tb], acc[ta][tb], 0, 0, 0);
        }
    }

    // --- epilogue: sim2 = 2*D*r_i*r_j; masked (j==i, j==i^NS) -> exp contributes 1
    float rc[4];
    int colg[4];
    #pragma unroll
    for (int tb = 0; tb < 4; ++tb) {
        colg[tb] = j0 + wc * 64 + tb * 16 + r16;
        rc[tb] = rnorm[colg[tb]];
    }
    float negacc = 0.f;
    float colacc[4] = {0.f, 0.f, 0.f, 0.f};
    #pragma unroll
    for (int ta = 0; ta < 4; ++ta) {
        #pragma unroll
        for (int r = 0; r < 4; ++r) {
            const int rowl = wr * 64 + ta * 16 + quad * 4 + r;
            const int rowg = i0 + rowl;
            const float rr = rnorm[rowg] * TEMP_INV;
            float rowe = 0.f;
            #pragma unroll
            for (int tb = 0; tb < 4; ++tb) {
                const float sim2 = acc[ta][tb][r] * rr * rc[tb];
                const bool masked = (colg[tb] == rowg) || (colg[tb] == (rowg ^ NS));
                const float e = masked ? 1.0f : __expf(sim2);
                rowe   += e;
                negacc += masked ? 0.0f : sim2;
                colacc[tb] += e;
            }
            #pragma unroll
            for (int off = 1; off < 16; off <<= 1)
                rowe += __shfl_xor(rowe, off, 64);
            if (r16 == 0) sRow[wc][rowl] = rowe;
        }
    }
    #pragma unroll
    for (int tb = 0; tb < 4; ++tb) {
        colacc[tb] += __shfl_xor(colacc[tb], 16, 64);
        colacc[tb] += __shfl_xor(colacc[tb], 32, 64);
        if (quad == 0) sCol[wr][wc * 64 + tb * 16 + r16] = colacc[tb];
    }
    if (offdiag) negacc *= 2.0f;
    #pragma unroll
    for (int off = 1; off < 64; off <<= 1)
        negacc += __shfl_xor(negacc, off, 64);
    if (lane == 0) sNeg[wv] = negacc;

    __syncthreads();

    if (t < TILE) {
        atomicAdd(&rowsum[i0 + t], sRow[0][t] + sRow[1][t]);
        if (offdiag)
            atomicAdd(&rowsum[j0 + t], sCol[0][t] + sCol[1][t]);
    }
    if (t == 0)
        negpart[id] = sNeg[0] + sNeg[1] + sNeg[2] + sNeg[3];
}

// ---------------------------------------------------------------------------
// Kernel 3: final scalars. E_i = rowsum[i] (includes +2 from masked entries).
// ---------------------------------------------------------------------------
__global__ __launch_bounds__(1024) void final_kernel(
        const float* __restrict__ rowsum, const float* __restrict__ rnorm,
        const float* __restrict__ posdot, const float* __restrict__ negpart,
        float* __restrict__ out) {
    const int t = threadIdx.x;
    float lsum = 0.f, psum = 0.f, nsum = 0.f;
    #pragma unroll
    for (int i = t; i < NI; i += 1024) {
        const int s = i & (NS - 1);
        const float sp = posdot[s] * rnorm[i] * rnorm[i ^ NS] * TEMP_INV;
        const float E = rowsum[i];
        lsum += logf(expf(sp) + E) - sp;
        psum += sp;
    }
    for (int i = t; i < NTRI; i += 1024)
        nsum += negpart[i];
    __shared__ float red[3][16];
    #pragma unroll
    for (int off = 32; off; off >>= 1) {
        lsum += __shfl_down(lsum, off, 64);
        psum += __shfl_down(psum, off, 64);
        nsum += __shfl_down(nsum, off, 64);
    }
    if ((t & 63) == 0) {
        red[0][t >> 6] = lsum; red[1][t >> 6] = psum; red[2][t >> 6] = nsum;
    }
    __syncthreads();
    if (t == 0) {
        lsum = 0.f; psum = 0.f; nsum = 0.f;
        #pragma unroll
        for (int w = 0; w < 16; ++w) {
            lsum += red[0][w]; psum += red[1][w]; nsum += red[2][w];
        }
        out[0] = lsum / (float)NI;
        out[1] = psum / (float)NI;
        out[2] = nsum / ((float)NI * (float)(NI - 2));
    }
}

// ---------------------------------------------------------------------------
extern "C" void kernel_launch(void* const* d_in, const int* in_sizes, int n_in,
                              void* d_out, int out_size, void* d_ws, size_t ws_size,
                              hipStream_t stream) {
    const float* x1 = (const float*)d_in[0];
    const float* x2 = (const float*)d_in[1];
    float* out = (float*)d_out;

    char* ws = (char*)d_ws;
    __hip_bfloat16* Xb = (__hip_bfloat16*)ws;                 // NI*DIM*2 = 8 MB
    float* rnorm  = (float*)(ws + (size_t)NI * DIM * 2);      // NI
    float* posdot = rnorm + NI;                               // NS
    float* rowsum = posdot + NS;                              // NI (zeroed in prep)
    float* negpart = rowsum + NI;                             // NTRI (all written)

    prep_kernel<<<NS / 2, 256, 0, stream>>>(x1, x2, Xb, rnorm, posdot, rowsum);

    sim_kernel<<<NTRI, 256, 0, stream>>>(Xb, rnorm, rowsum, negpart);

    final_kernel<<<1, 1024, 0, stream>>>(rowsum, rnorm, posdot, negpart, out);
}